// Round 1
// baseline (740.635 us; speedup 1.0000x reference)
//
#include <hip/hip_runtime.h>
#include <cstdint>
#include <cstddef>

// LSTM cell: B=16384, D=1024, H=1024.
// pre[b, k*H+j] = sum_d x[b,d] Wi[k,j,d] + sum_h h[b,h] Wh[k,j,h] + bi[k,j]
// => one GEMM: A[16384][2048] = [x|h] (bf16), Bt[4096][2048] = [Wi|Wh] (bf16, row n=k*1024+j)
// Epilogue fused into GEMM: block tile = 128 rows x (4 gates x 32 j), so all 4 gates
// of a (b,j) live in the SAME lane across col-fragments {p, p+2, p+4, p+6}.

typedef float f32x4 __attribute__((ext_vector_type(4)));
typedef __bf16 bf16x8 __attribute__((ext_vector_type(8)));
typedef unsigned short us4 __attribute__((ext_vector_type(4)));

static __device__ __forceinline__ unsigned short f2bf(float f) {
  unsigned int u = __float_as_uint(f);
  u += 0x7fffu + ((u >> 16) & 1u);   // RNE (finite inputs)
  return (unsigned short)(u >> 16);
}

static __device__ __forceinline__ float fast_sigmoid(float x) {
  return 1.0f / (1.0f + __expf(-x));
}
static __device__ __forceinline__ float fast_tanh(float x) {
  float e = __expf(2.0f * x);
  return 1.0f - 2.0f / (e + 1.0f);
}

static __device__ __forceinline__ void gload16(const void* g, void* l) {
  __builtin_amdgcn_global_load_lds(
      (const __attribute__((address_space(1))) void*)g,
      (__attribute__((address_space(3))) void*)l, 16, 0, 0);
}

// ---- conversion: Wi[4M f32], Wh[4M f32] -> Bt bf16 [4096][2048] ----
__global__ void conv_w(const float* __restrict__ Wi, const float* __restrict__ Wh,
                       unsigned short* __restrict__ Bt) {
  int g = blockIdx.x * blockDim.x + threadIdx.x;   // 2M float4-groups
  const int HALF = 1024 * 1024;                    // groups per matrix
  const float* src = (g < HALF) ? Wi : Wh;
  int off = (g < HALF) ? 0 : 1024;
  int gi = (g < HALF) ? g : g - HALF;
  float4 v = reinterpret_cast<const float4*>(src)[gi];
  int e = gi * 4;
  int n = e >> 10;
  int d = e & 1023;
  us4 o;
  o.x = f2bf(v.x); o.y = f2bf(v.y); o.z = f2bf(v.z); o.w = f2bf(v.w);
  *reinterpret_cast<us4*>(&Bt[(size_t)n * 2048 + off + d]) = o;
}

// ---- conversion: x[16M f32], h[16M f32] -> A bf16 [16384][2048] ----
__global__ void conv_a(const float* __restrict__ x, const float* __restrict__ h,
                       unsigned short* __restrict__ A) {
  int g = blockIdx.x * blockDim.x + threadIdx.x;   // 8M float4-groups
  const int HALF = 4 * 1024 * 1024;
  const float* src = (g < HALF) ? x : h;
  int off = (g < HALF) ? 0 : 1024;
  int gi = (g < HALF) ? g : g - HALF;
  float4 v = reinterpret_cast<const float4*>(src)[gi];
  int e = gi * 4;
  int b = e >> 10;
  int d = e & 1023;
  us4 o;
  o.x = f2bf(v.x); o.y = f2bf(v.y); o.z = f2bf(v.z); o.w = f2bf(v.w);
  *reinterpret_cast<us4*>(&A[(size_t)b * 2048 + off + d]) = o;
}

// ---- fused GEMM + LSTM epilogue ----
// grid: (32, 128); block: 256 (4 waves). Tile 128x128, BK=32.
// Block cols: cc in [0,128): gate k = cc>>5, j = bx*32 + (cc&31); Bt row n = k*1024 + j.
__global__ __launch_bounds__(256) void lstm_gemm(
    const unsigned short* __restrict__ A,   // [16384][2048] bf16
    const unsigned short* __restrict__ Bt,  // [4096][2048] bf16
    const float* __restrict__ bi,           // [4][1024] f32
    const float* __restrict__ cin,          // [16384][1024] f32
    float* __restrict__ out)                // o | new_h | new_c, each [16384][1024] f32
{
  __shared__ unsigned short As[128][32];   // 8 KB
  __shared__ unsigned short Bs[128][32];   // 8 KB

  const int tid  = threadIdx.x;
  const int wave = tid >> 6;
  const int lane = tid & 63;
  const int bx = blockIdx.x;     // col tile: j0 = bx*32
  const int by = blockIdx.y;     // row tile
  const int row0 = by * 128;
  const int j0 = bx * 32;

  // staging: 8 chunks of 16 rows x 32 k (1024 B each); wave w owns chunks 2w, 2w+1
  const int lrow = lane >> 2;          // row within chunk
  const int lk   = (lane & 3) * 8;     // k element offset (16 B per lane)
  const int c0 = wave * 2;
  const int c1 = wave * 2 + 1;
  const int cc0 = c0 * 16 + lrow;      // row (A) / col (B) within block tile
  const int cc1 = c1 * 16 + lrow;

  const size_t an0 = (size_t)(row0 + cc0) * 2048 + lk;
  const size_t an1 = (size_t)(row0 + cc1) * 2048 + lk;
  const size_t bn0 = (size_t)((cc0 >> 5) * 1024 + j0 + (cc0 & 31)) * 2048 + lk;
  const size_t bn1 = (size_t)((cc1 >> 5) * 1024 + j0 + (cc1 & 31)) * 2048 + lk;

  char* lAs0 = (char*)&As[0][0] + c0 * 1024;
  char* lAs1 = (char*)&As[0][0] + c1 * 1024;
  char* lBs0 = (char*)&Bs[0][0] + c0 * 1024;
  char* lBs1 = (char*)&Bs[0][0] + c1 * 1024;

  const int fl = lane & 15;     // A-row / B-col within fragment
  const int q  = lane >> 4;     // k-group: k = q*8..q*8+7 ; D-rows q*4+r

  f32x4 acc[2][8];
#pragma unroll
  for (int m = 0; m < 2; ++m)
#pragma unroll
    for (int n = 0; n < 8; ++n) acc[m][n] = (f32x4){0.f, 0.f, 0.f, 0.f};

  for (int kt = 0; kt < 64; ++kt) {
    const int koff = kt * 32;
    gload16(A + an0 + koff, lAs0);
    gload16(A + an1 + koff, lAs1);
    gload16(Bt + bn0 + koff, lBs0);
    gload16(Bt + bn1 + koff, lBs1);
    __syncthreads();   // drains vmcnt -> staged tile visible

    bf16x8 af[2], bf[8];
#pragma unroll
    for (int mr = 0; mr < 2; ++mr)
      af[mr] = *reinterpret_cast<const bf16x8*>(&As[wave * 32 + mr * 16 + fl][q * 8]);
#pragma unroll
    for (int fc = 0; fc < 8; ++fc)
      bf[fc] = *reinterpret_cast<const bf16x8*>(&Bs[fc * 16 + fl][q * 8]);
#pragma unroll
    for (int mr = 0; mr < 2; ++mr)
#pragma unroll
      for (int fc = 0; fc < 8; ++fc)
        acc[mr][fc] = __builtin_amdgcn_mfma_f32_16x16x32_bf16(af[mr], bf[fc], acc[mr][fc], 0, 0, 0);

    __syncthreads();   // protect LDS from next stage
  }

  // ---- epilogue: per lane, gates i/f/g/o are col-fragments {p, p+2, p+4, p+6} ----
  const size_t OUT_H = (size_t)16384 * 1024;
#pragma unroll
  for (int mr = 0; mr < 2; ++mr) {
#pragma unroll
    for (int p = 0; p < 2; ++p) {
      const int j = j0 + p * 16 + fl;
      const float bii = bi[0 * 1024 + j];
      const float bif = bi[1 * 1024 + j];
      const float big = bi[2 * 1024 + j];
      const float bio = bi[3 * 1024 + j];
#pragma unroll
      for (int r = 0; r < 4; ++r) {
        const int brow = row0 + wave * 32 + mr * 16 + q * 4 + r;
        const float pi = acc[mr][p][r]     + bii;
        const float pf = acc[mr][p + 2][r] + bif;
        const float pg = acc[mr][p + 4][r] + big;
        const float po = acc[mr][p + 6][r] + bio;
        const float iv = fast_sigmoid(pi);
        const float fv = fast_sigmoid(pf);
        const float gv = fast_tanh(pg);
        const float ov = fast_sigmoid(po);
        const float cv = cin[(size_t)brow * 1024 + j];
        const float nc = fv * cv + iv * gv;
        const float nh = ov * fast_tanh(nc);
        const size_t oi = (size_t)brow * 1024 + j;
        out[oi] = ov;
        out[OUT_H + oi] = nh;
        out[2 * OUT_H + oi] = nc;
      }
    }
  }
}

extern "C" void kernel_launch(void* const* d_in, const int* in_sizes, int n_in,
                              void* d_out, int out_size, void* d_ws, size_t ws_size,
                              hipStream_t stream) {
  const float* x  = (const float*)d_in[0];
  const float* h  = (const float*)d_in[1];
  const float* c  = (const float*)d_in[2];
  const float* Wi = (const float*)d_in[3];
  const float* bi = (const float*)d_in[4];
  const float* Wh = (const float*)d_in[5];
  float* out = (float*)d_out;

  // workspace: Bt bf16 [4096][2048] = 16 MB, then A bf16 [16384][2048] = 64 MB
  unsigned short* Bt = (unsigned short*)d_ws;
  unsigned short* A  = (unsigned short*)d_ws + (size_t)8 * 1024 * 1024;

  conv_w<<<8192, 256, 0, stream>>>(Wi, Wh, Bt);
  conv_a<<<32768, 256, 0, stream>>>(x, h, A);

  dim3 grid(32, 128);
  lstm_gemm<<<grid, 256, 0, stream>>>(A, Bt, bi, c, out);
}